// Round 1
// baseline (29527.759 us; speedup 1.0000x reference)
//
#include <hip/hip_runtime.h>
#include <cstdint>
#include <cstddef>

// RNG scheme: 1 = modern JAX (jax_threefry_partitionable=True, default since ~0.4.30)
//             0 = legacy threefry counter layout
#ifndef PARTITIONABLE
#define PARTITIONABLE 1
#endif

namespace {
constexpr int kBatch  = 4096;
constexpr int kEmb    = 128;
constexpr int kHid    = 512;
constexpr int kVoc    = 2048;
constexpr int kMaxLen = 64;
constexpr int kTopK   = 40;
constexpr int kBos = 1, kEos = 2, kPad = 0;
constexpr int kEffMin = 20;               // min(min_generation_length, max_len-2)
constexpr float kNeg  = -1.0e9f;
constexpr float kTiny = 1.17549435082228751e-38f;
}

__host__ __device__ inline void tf2x32(uint32_t k0, uint32_t k1,
                                       uint32_t x0, uint32_t x1,
                                       uint32_t& o0, uint32_t& o1) {
  uint32_t ks0 = k0, ks1 = k1, ks2 = k0 ^ k1 ^ 0x1BD11BDAu;
  x0 += ks0; x1 += ks1;
#define TFR(r) { x0 += x1; x1 = (x1 << (r)) | (x1 >> (32 - (r))); x1 ^= x0; }
  TFR(13) TFR(15) TFR(26) TFR(6)   x0 += ks1; x1 += ks2 + 1u;
  TFR(17) TFR(29) TFR(16) TFR(24)  x0 += ks2; x1 += ks0 + 2u;
  TFR(13) TFR(15) TFR(26) TFR(6)   x0 += ks0; x1 += ks1 + 3u;
  TFR(17) TFR(29) TFR(16) TFR(24)  x0 += ks1; x1 += ks2 + 4u;
  TFR(13) TFR(15) TFR(26) TFR(6)   x0 += ks2; x1 += ks0 + 5u;
#undef TFR
  o0 = x0; o1 = x1;
}

// XLA's f32 tanh: rational poly, clamp [-9,9], |x|<4e-4 -> x. No FMA contraction.
__device__ __forceinline__ float xla_tanh(float x) {
  float ax = fabsf(x);
  float xc = fminf(fmaxf(x, -9.0f), 9.0f);
  float x2 = __fmul_rn(xc, xc);
  float num = -2.76076847742355e-16f;
  num = __fadd_rn(__fmul_rn(x2, num), 2.00018790482477e-13f);
  num = __fadd_rn(__fmul_rn(x2, num), -8.60467152213735e-11f);
  num = __fadd_rn(__fmul_rn(x2, num), 5.12229709037114e-08f);
  num = __fadd_rn(__fmul_rn(x2, num), 1.48572235717979e-05f);
  num = __fadd_rn(__fmul_rn(x2, num), 6.37261928875436e-04f);
  num = __fadd_rn(__fmul_rn(x2, num), 4.89352455891786e-03f);
  num = __fmul_rn(xc, num);
  float den = 1.19825839466702e-06f;
  den = __fadd_rn(__fmul_rn(x2, den), 1.18534705686654e-04f);
  den = __fadd_rn(__fmul_rn(x2, den), 2.26843463243900e-03f);
  den = __fadd_rn(__fmul_rn(x2, den), 4.89352518554385e-03f);
  return (ax < 4.0e-04f) ? x : __fdiv_rn(num, den);
}

// XLA LogisticExpander: 1 / (1 + exp(-x)), no contraction.
__device__ __forceinline__ float xla_sigmoid(float x) {
  return __fdiv_rn(1.0f, __fadd_rn(1.0f, expf(-x)));
}

// C[M,N] = act(A[M,K] * Bw[N,K]^T + bias[N]).  Tiles: BM=128, BN=64, BK=16.
// 256 threads, 8x4 micro-tile per thread. Sequential-k accumulation per output.
template <int ACT>
__global__ __launch_bounds__(256) void gemm_nt(
    const float* __restrict__ A, int lda,
    const float* __restrict__ Bw, int ldb,
    const float* __restrict__ bias,
    float* __restrict__ C, int ldc,
    int M, int N, int K) {
  __shared__ float As[128 * 20];   // row-major, stride 20 (pad)
  __shared__ float Bs[16 * 64];    // transposed: [k][n]
  const int tid = threadIdx.x;
  const int tx = tid & 15;         // cols 4*tx .. 4*tx+3
  const int ty = tid >> 4;         // rows ty + 16*i
  const int bm = blockIdx.y * 128;
  const int bn = blockIdx.x * 64;
  const int lr = tid >> 2;         // 0..63
  const int lc = (tid & 3) * 4;    // 0,4,8,12

  float acc[8][4];
#pragma unroll
  for (int i = 0; i < 8; ++i)
#pragma unroll
    for (int j = 0; j < 4; ++j) acc[i][j] = 0.0f;

  for (int k0 = 0; k0 < K; k0 += 16) {
    float4 a0 = *(const float4*)(A + (size_t)(bm + lr) * lda + k0 + lc);
    float4 a1 = *(const float4*)(A + (size_t)(bm + lr + 64) * lda + k0 + lc);
    float4 b0 = *(const float4*)(Bw + (size_t)(bn + lr) * ldb + k0 + lc);
    *(float4*)&As[lr * 20 + lc] = a0;
    *(float4*)&As[(lr + 64) * 20 + lc] = a1;
    Bs[(lc + 0) * 64 + lr] = b0.x;
    Bs[(lc + 1) * 64 + lr] = b0.y;
    Bs[(lc + 2) * 64 + lr] = b0.z;
    Bs[(lc + 3) * 64 + lr] = b0.w;
    __syncthreads();
#pragma unroll
    for (int kq = 0; kq < 4; ++kq) {
      float4 av[8];
#pragma unroll
      for (int i = 0; i < 8; ++i)
        av[i] = *(const float4*)&As[(ty + 16 * i) * 20 + 4 * kq];
      float4 bv[4];
#pragma unroll
      for (int q = 0; q < 4; ++q)
        bv[q] = *(const float4*)&Bs[(4 * kq + q) * 64 + tx * 4];
#pragma unroll
      for (int i = 0; i < 8; ++i) {
        float4 a = av[i];
        acc[i][0] += a.x * bv[0].x; acc[i][1] += a.x * bv[0].y;
        acc[i][2] += a.x * bv[0].z; acc[i][3] += a.x * bv[0].w;
        acc[i][0] += a.y * bv[1].x; acc[i][1] += a.y * bv[1].y;
        acc[i][2] += a.y * bv[1].z; acc[i][3] += a.y * bv[1].w;
        acc[i][0] += a.z * bv[2].x; acc[i][1] += a.z * bv[2].y;
        acc[i][2] += a.z * bv[2].z; acc[i][3] += a.z * bv[2].w;
        acc[i][0] += a.w * bv[3].x; acc[i][1] += a.w * bv[3].y;
        acc[i][2] += a.w * bv[3].z; acc[i][3] += a.w * bv[3].w;
      }
    }
    __syncthreads();
  }
  const int c = bn + tx * 4;
  const float4 bsv = *(const float4*)(bias + c);
#pragma unroll
  for (int i = 0; i < 8; ++i) {
    const int r = bm + ty + 16 * i;
    float4 o;
    o.x = acc[i][0] + bsv.x; o.y = acc[i][1] + bsv.y;
    o.z = acc[i][2] + bsv.z; o.w = acc[i][3] + bsv.w;
    if (ACT == 1) { o.x = xla_tanh(o.x); o.y = xla_tanh(o.y);
                    o.z = xla_tanh(o.z); o.w = xla_tanh(o.w); }
    *(float4*)(C + (size_t)r * ldc + c) = o;
  }
}

// GRU gate fusion: h' = (1-u)*n + u*h, gates (r,z,n) split over 1536 cols.
__global__ __launch_bounds__(256) void k_gates(
    const float* __restrict__ gi_mat, const int* __restrict__ gi_rows,
    const float* __restrict__ gh, const float* __restrict__ h_in,
    float* __restrict__ h_out) {
  int idx = blockIdx.x * 256 + threadIdx.x;       // over 4096*512
  int b = idx >> 9, j = idx & 511;
  int gr = gi_rows ? gi_rows[b] : b;
  const float* gi = gi_mat + (size_t)gr * 1536;
  const float* gp = gh + (size_t)b * 1536;
  float ir = gi[j], iz = gi[512 + j], in_ = gi[1024 + j];
  float hr = gp[j], hz = gp[512 + j], hn = gp[1024 + j];
  float r = xla_sigmoid(__fadd_rn(ir, hr));
  float u = xla_sigmoid(__fadd_rn(iz, hz));
  float n = xla_tanh(__fadd_rn(in_, __fmul_rn(r, hn)));
  float h = h_in[(size_t)b * 512 + j];
  float t1 = __fmul_rn(__fsub_rn(1.0f, u), n);
  float t2 = __fmul_rn(u, h);
  h_out[(size_t)b * 512 + j] = __fadd_rn(t1, t2);
}

// Per-row: mask, top-k threshold (bitwise radix search), gumbel+argmax, token update.
__global__ __launch_bounds__(256) void k_sample(
    const float* __restrict__ logits, int* __restrict__ cur,
    int* __restrict__ finished, int* __restrict__ outTok,
    int t, uint32_t sk0, uint32_t sk1) {
  const int row = blockIdx.x;
  const int tid = threadIdx.x;
  __shared__ float sl[kVoc];
  __shared__ uint32_t skeys[kVoc];
  __shared__ int   redi[4];
  __shared__ float redf[4];
  __shared__ int   redix[4];

  const float* lp = logits + (size_t)row * kVoc;
  for (int c = tid; c < kVoc; c += 256) {
    float v = lp[c];
    if (c == kBos || c == kPad) v = kNeg;
    if (c == kEos && t < 1 + kEffMin) v = kNeg;
    sl[c] = v;
    uint32_t u = __float_as_uint(v);
    skeys[c] = u ^ ((u >> 31) ? 0xFFFFFFFFu : 0x80000000u);  // order-preserving
  }
  __syncthreads();

  // 40th-largest key: greedy bitwise search for max T with count(key>=T) >= 40
  uint32_t prefix = 0u;
  for (int b = 31; b >= 0; --b) {
    uint32_t trial = prefix | (1u << b);
    int cnt = 0;
    for (int c = tid; c < kVoc; c += 256) cnt += (skeys[c] >= trial) ? 1 : 0;
#pragma unroll
    for (int off = 32; off; off >>= 1) cnt += __shfl_down(cnt, off, 64);
    __syncthreads();
    if ((tid & 63) == 0) redi[tid >> 6] = cnt;
    __syncthreads();
    int total = redi[0] + redi[1] + redi[2] + redi[3];
    if (total >= kTopK) prefix = trial;
  }

  // gumbel + argmax over kept entries
  float best = -3.4e38f; int bidx = kVoc;
  for (int c = tid; c < kVoc; c += 256) {
    if (skeys[c] >= prefix) {
      uint32_t idx = (uint32_t)row * (uint32_t)kVoc + (uint32_t)c;
      uint32_t w1, w2, bits;
#if PARTITIONABLE
      tf2x32(sk0, sk1, 0u, idx, w1, w2);
      bits = w1 ^ w2;
#else
      const uint32_t HH = (uint32_t)((uint64_t)kBatch * kVoc / 2);
      if (idx < HH) { tf2x32(sk0, sk1, idx, idx + HH, w1, w2); bits = w1; }
      else          { tf2x32(sk0, sk1, idx - HH, idx, w1, w2); bits = w2; }
#endif
      uint32_t fb = (bits >> 9) | 0x3f800000u;
      float uf = __fsub_rn(__uint_as_float(fb), 1.0f);
      if (uf == 0.0f) uf = kTiny;
      float g = -logf(-logf(uf));
      float tot = __fadd_rn(g, sl[c]);
      if (tot > best || (tot == best && c < bidx)) { best = tot; bidx = c; }
    }
  }
#pragma unroll
  for (int off = 32; off; off >>= 1) {
    float ov = __shfl_down(best, off, 64);
    int   oi = __shfl_down(bidx, off, 64);
    if (ov > best || (ov == best && oi < bidx)) { best = ov; bidx = oi; }
  }
  if ((tid & 63) == 0) { redf[tid >> 6] = best; redix[tid >> 6] = bidx; }
  __syncthreads();
  if (tid == 0) {
    for (int w = 1; w < 4; ++w) {
      if (redf[w] > best || (redf[w] == best && redix[w] < bidx)) {
        best = redf[w]; bidx = redix[w];
      }
    }
    int fin = finished[row];
    int nxt = fin ? kPad : bidx;
    outTok[(size_t)row * kMaxLen + t] = nxt;
    cur[row] = nxt;
    finished[row] = fin | (nxt == kEos);
  }
}

__global__ __launch_bounds__(256) void k_init(int* cur, int* finished, int* outTok) {
  int i = blockIdx.x * 256 + threadIdx.x;
  if (i < kBatch) {
    cur[i] = kBos;
    finished[i] = 0;
    outTok[(size_t)i * kMaxLen] = kBos;
  }
}

extern "C" void kernel_launch(void* const* d_in, const int* in_sizes, int n_in,
                              void* d_out, int out_size, void* d_ws, size_t ws_size,
                              hipStream_t stream) {
  (void)in_sizes; (void)n_in; (void)out_size; (void)ws_size;
  const float* z      = (const float*)d_in[0];
  const float* embed  = (const float*)d_in[1];
  const float* w_lh   = (const float*)d_in[2];
  const float* b_lh   = (const float*)d_in[3];
  const float* w_ih0  = (const float*)d_in[4];
  const float* w_hh0  = (const float*)d_in[5];
  const float* b_ih0  = (const float*)d_in[6];
  const float* b_hh0  = (const float*)d_in[7];
  const float* w_ih1  = (const float*)d_in[8];
  const float* w_hh1  = (const float*)d_in[9];
  const float* b_ih1  = (const float*)d_in[10];
  const float* b_hh1  = (const float*)d_in[11];
  const float* w_out  = (const float*)d_in[12];
  const float* b_out  = (const float*)d_in[13];
  int* out = (int*)d_out;

  // workspace layout (floats)
  float* Eih0 = (float*)d_ws;                         // 2048*1536
  float* h0A  = Eih0 + (size_t)kVoc * 1536;           // 4096*512 each
  float* h0B  = h0A + (size_t)kBatch * kHid;
  float* h1A  = h0B + (size_t)kBatch * kHid;
  float* h1B  = h1A + (size_t)kBatch * kHid;
  float* gh   = h1B + (size_t)kBatch * kHid;          // 4096*1536
  float* gi1  = gh + (size_t)kBatch * 1536;           // 4096*1536
  float* logits = gh;                                 // alias: dead by the time logits写
  int* curTok   = (int*)(gi1 + (size_t)kBatch * 1536);
  int* finished = curTok + kBatch;

  dim3 blk(256);

  // Eih0 = embed @ w_ih0^T + b_ih0   [2048, 1536]
  gemm_nt<0><<<dim3(1536 / 64, kVoc / 128), blk, 0, stream>>>(
      embed, kEmb, w_ih0, kEmb, b_ih0, Eih0, 1536, kVoc, 1536, kEmb);
  // h0 = tanh(z @ w_lh[0:512]^T + b_lh[0:512]); h1 likewise
  gemm_nt<1><<<dim3(kHid / 64, kBatch / 128), blk, 0, stream>>>(
      z, kEmb, w_lh, kEmb, b_lh, h0A, kHid, kBatch, kHid, kEmb);
  gemm_nt<1><<<dim3(kHid / 64, kBatch / 128), blk, 0, stream>>>(
      z, kEmb, w_lh + (size_t)kHid * kEmb, kEmb, b_lh + kHid, h1A, kHid, kBatch, kHid, kEmb);
  k_init<<<dim3((kBatch + 255) / 256), blk, 0, stream>>>(curTok, finished, out);

  uint32_t key0 = 0u, key1 = 1u;   // jax.random.key(1)
  for (int t = 1; t < kMaxLen; ++t) {
    uint32_t nk0, nk1, s0, s1;
#if PARTITIONABLE
    tf2x32(key0, key1, 0u, 0u, nk0, nk1);
    tf2x32(key0, key1, 0u, 1u, s0, s1);
#else
    uint32_t a0, b0w, a1, b1w;
    tf2x32(key0, key1, 0u, 2u, a0, b0w);
    tf2x32(key0, key1, 1u, 3u, a1, b1w);
    nk0 = a0; nk1 = a1; s0 = b0w; s1 = b1w;
#endif
    const float* h0in = (t & 1) ? h0A : h0B;  float* h0out = (t & 1) ? h0B : h0A;
    const float* h1in = (t & 1) ? h1A : h1B;  float* h1out = (t & 1) ? h1B : h1A;

    // layer 0
    gemm_nt<0><<<dim3(1536 / 64, kBatch / 128), blk, 0, stream>>>(
        h0in, kHid, w_hh0, kHid, b_hh0, gh, 1536, kBatch, 1536, kHid);
    k_gates<<<dim3(kBatch * kHid / 256), blk, 0, stream>>>(Eih0, curTok, gh, h0in, h0out);
    // layer 1
    gemm_nt<0><<<dim3(1536 / 64, kBatch / 128), blk, 0, stream>>>(
        h0out, kHid, w_ih1, kHid, b_ih1, gi1, 1536, kBatch, 1536, kHid);
    gemm_nt<0><<<dim3(1536 / 64, kBatch / 128), blk, 0, stream>>>(
        h1in, kHid, w_hh1, kHid, b_hh1, gh, 1536, kBatch, 1536, kHid);
    k_gates<<<dim3(kBatch * kHid / 256), blk, 0, stream>>>(gi1, nullptr, gh, h1in, h1out);
    // logits + sample
    gemm_nt<0><<<dim3(kVoc / 64, kBatch / 128), blk, 0, stream>>>(
        h1out, kHid, w_out, kHid, b_out, logits, kVoc, kBatch, kVoc, kHid);
    k_sample<<<dim3(kBatch), blk, 0, stream>>>(logits, curTok, finished, out, t, s0, s1);

    key0 = nk0; key1 = nk1;
  }
}

// Round 2
// 28159.314 us; speedup vs baseline: 1.0486x; 1.0486x over previous
//
#include <hip/hip_runtime.h>
#include <cstdint>
#include <cstddef>

#ifndef PARTITIONABLE
#define PARTITIONABLE 1
#endif

namespace {
constexpr int kBatch  = 4096;
constexpr int kEmb    = 128;
constexpr int kHid    = 512;
constexpr int kVoc    = 2048;
constexpr int kMaxLen = 64;
constexpr int kTopK   = 40;
constexpr int kBos = 1, kEos = 2, kPad = 0;
constexpr int kEffMin = 20;
constexpr float kNeg  = -1.0e9f;
constexpr float kTiny = 1.17549435082228751e-38f;
}

__host__ __device__ inline void tf2x32(uint32_t k0, uint32_t k1,
                                       uint32_t x0, uint32_t x1,
                                       uint32_t& o0, uint32_t& o1) {
  uint32_t ks0 = k0, ks1 = k1, ks2 = k0 ^ k1 ^ 0x1BD11BDAu;
  x0 += ks0; x1 += ks1;
#define TFR(r) { x0 += x1; x1 = (x1 << (r)) | (x1 >> (32 - (r))); x1 ^= x0; }
  TFR(13) TFR(15) TFR(26) TFR(6)   x0 += ks1; x1 += ks2 + 1u;
  TFR(17) TFR(29) TFR(16) TFR(24)  x0 += ks2; x1 += ks0 + 2u;
  TFR(13) TFR(15) TFR(26) TFR(6)   x0 += ks0; x1 += ks1 + 3u;
  TFR(17) TFR(29) TFR(16) TFR(24)  x0 += ks1; x1 += ks2 + 4u;
  TFR(13) TFR(15) TFR(26) TFR(6)   x0 += ks2; x1 += ks0 + 5u;
#undef TFR
  o0 = x0; o1 = x1;
}

__device__ __forceinline__ float xla_tanh(float x) {
  float ax = fabsf(x);
  float xc = fminf(fmaxf(x, -9.0f), 9.0f);
  float x2 = __fmul_rn(xc, xc);
  float num = -2.76076847742355e-16f;
  num = __fadd_rn(__fmul_rn(x2, num), 2.00018790482477e-13f);
  num = __fadd_rn(__fmul_rn(x2, num), -8.60467152213735e-11f);
  num = __fadd_rn(__fmul_rn(x2, num), 5.12229709037114e-08f);
  num = __fadd_rn(__fmul_rn(x2, num), 1.48572235717979e-05f);
  num = __fadd_rn(__fmul_rn(x2, num), 6.37261928875436e-04f);
  num = __fadd_rn(__fmul_rn(x2, num), 4.89352455891786e-03f);
  num = __fmul_rn(xc, num);
  float den = 1.19825839466702e-06f;
  den = __fadd_rn(__fmul_rn(x2, den), 1.18534705686654e-04f);
  den = __fadd_rn(__fmul_rn(x2, den), 2.26843463243900e-03f);
  den = __fadd_rn(__fmul_rn(x2, den), 4.89352518554385e-03f);
  return (ax < 4.0e-04f) ? x : __fdiv_rn(num, den);
}

__device__ __forceinline__ float xla_sigmoid(float x) {
  return __fdiv_rn(1.0f, __fadd_rn(1.0f, expf(-x)));
}

__device__ __forceinline__ void gl_lds16(const float* g, float* l) {
  __builtin_amdgcn_global_load_lds(
      (__attribute__((address_space(1))) void*)g,
      (__attribute__((address_space(3))) void*)l, 16, 0, 0);
}

// C[M,N] = act(A[M,K] @ Bt[K,N] + bias[N]); A row-major lda, Bt row-major ldb.
// BM=128, BN=128, BK=16, 256 threads, 8x8 micro-tile, double-buffered LDS,
// global_load_lds staging; A source-side XOR-swizzled (granule ^= row&3).
// dual: blockIdx.z selects parameter set (for independent same-shape GEMMs).
template <int ACT>
__global__ __launch_bounds__(256) void gemm2(
    const float* __restrict__ A0, const float* __restrict__ B0,
    const float* __restrict__ bias0, float* __restrict__ C0,
    const float* __restrict__ A1, const float* __restrict__ B1,
    const float* __restrict__ bias1, float* __restrict__ C1,
    int lda, int ldb, int ldc, int K) {
  __shared__ __attribute__((aligned(16))) float As[2][128 * 16];
  __shared__ __attribute__((aligned(16))) float Bs[2][16 * 128];

  const float* A    = blockIdx.z ? A1 : A0;
  const float* Bt   = blockIdx.z ? B1 : B0;
  const float* bias = blockIdx.z ? bias1 : bias0;
  float*       C    = blockIdx.z ? C1 : C0;

  const int tid = threadIdx.x;
  const int w = tid >> 6, l = tid & 63;
  const int bm = blockIdx.y * 128;
  const int bn = blockIdx.x * 128;
  const int tx = tid & 15, ty = tid >> 4;
  const int t3 = ty & 3;

  // A staging map (per issue i in {0,1}): lds float off = (i*4+w)*256 + l*4
  //   -> row = (i*4+w)*16 + l/4, slot = l%4; source granule = slot ^ (row&3)
  const int arow  = w * 16 + (l >> 2);
  const int agran = (l & 3) ^ ((l >> 2) & 3);
  const float* pA = A + (size_t)(bm + arow) * lda + agran * 4;
  // B staging map: k = (i*4+w)*2 + l/32, n = (l%32)*4 (linear, no swizzle)
  const int bk = w * 2 + (l >> 5);
  const int bnc = (l & 31) * 4;
  const float* pB = Bt + (size_t)bk * ldb + bn + bnc;

  float acc[8][8];
#pragma unroll
  for (int i = 0; i < 8; ++i)
#pragma unroll
    for (int j = 0; j < 8; ++j) acc[i][j] = 0.0f;

  const int nt = K >> 4;
  // prologue: stage tile 0 into buf 0
  gl_lds16(pA,            &As[0][w * 256]);
  gl_lds16(pA + 64 * lda, &As[0][(4 + w) * 256]);
  gl_lds16(pB,            &Bs[0][w * 256]);
  gl_lds16(pB + (size_t)8 * ldb, &Bs[0][(4 + w) * 256]);
  __syncthreads();

  for (int t = 0; t < nt; ++t) {
    const int cur = t & 1;
    if (t + 1 < nt) {
      const float* qA = pA + (t + 1) * 16;
      const float* qB = pB + (size_t)(t + 1) * 16 * ldb;
      gl_lds16(qA,            &As[cur ^ 1][w * 256]);
      gl_lds16(qA + 64 * lda, &As[cur ^ 1][(4 + w) * 256]);
      gl_lds16(qB,            &Bs[cur ^ 1][w * 256]);
      gl_lds16(qB + (size_t)8 * ldb, &Bs[cur ^ 1][(4 + w) * 256]);
    }
    const float* as = As[cur];
    const float* bs = Bs[cur];
#pragma unroll
    for (int g = 0; g < 4; ++g) {
      float4 bv0[4], bv1[4];
#pragma unroll
      for (int q = 0; q < 4; ++q) {
        bv0[q] = *(const float4*)&bs[(g * 4 + q) * 128 + tx * 4];
        bv1[q] = *(const float4*)&bs[(g * 4 + q) * 128 + 64 + tx * 4];
      }
#pragma unroll
      for (int ii = 0; ii < 8; ++ii) {
        float4 a = *(const float4*)&as[(ty + 16 * ii) * 16 + ((g ^ t3) * 4)];
        float ak[4] = {a.x, a.y, a.z, a.w};
#pragma unroll
        for (int q = 0; q < 4; ++q) {
          const float av_ = ak[q];
          const float4 b0 = bv0[q], b1 = bv1[q];
          acc[ii][0] += av_ * b0.x; acc[ii][1] += av_ * b0.y;
          acc[ii][2] += av_ * b0.z; acc[ii][3] += av_ * b0.w;
          acc[ii][4] += av_ * b1.x; acc[ii][5] += av_ * b1.y;
          acc[ii][6] += av_ * b1.z; acc[ii][7] += av_ * b1.w;
        }
      }
    }
    __syncthreads();
  }

  const int c0 = bn + tx * 4, c1 = bn + 64 + tx * 4;
  const float4 bs0 = *(const float4*)&bias[c0];
  const float4 bs1 = *(const float4*)&bias[c1];
#pragma unroll
  for (int ii = 0; ii < 8; ++ii) {
    const int r = bm + ty + 16 * ii;
    float4 o0, o1;
    o0.x = acc[ii][0] + bs0.x; o0.y = acc[ii][1] + bs0.y;
    o0.z = acc[ii][2] + bs0.z; o0.w = acc[ii][3] + bs0.w;
    o1.x = acc[ii][4] + bs1.x; o1.y = acc[ii][5] + bs1.y;
    o1.z = acc[ii][6] + bs1.z; o1.w = acc[ii][7] + bs1.w;
    if (ACT == 1) {
      o0.x = xla_tanh(o0.x); o0.y = xla_tanh(o0.y);
      o0.z = xla_tanh(o0.z); o0.w = xla_tanh(o0.w);
      o1.x = xla_tanh(o1.x); o1.y = xla_tanh(o1.y);
      o1.z = xla_tanh(o1.z); o1.w = xla_tanh(o1.w);
    }
    *(float4*)(C + (size_t)r * ldc + c0) = o0;
    *(float4*)(C + (size_t)r * ldc + c1) = o1;
  }
}

__global__ __launch_bounds__(256) void k_transpose(
    const float* __restrict__ in, float* __restrict__ out, int R, int C) {
  __shared__ float tile[32][33];
  int c0 = blockIdx.x * 32, r0 = blockIdx.y * 32;
  int x = threadIdx.x, y0 = threadIdx.y;
  for (int i = y0; i < 32; i += 8) {
    int r = r0 + i, c = c0 + x;
    tile[i][x] = (r < R && c < C) ? in[(size_t)r * C + c] : 0.0f;
  }
  __syncthreads();
  for (int i = y0; i < 32; i += 8) {
    int orow = c0 + i, oc = r0 + x;
    if (orow < C && oc < R) out[(size_t)orow * R + oc] = tile[x][i];
  }
}

__global__ __launch_bounds__(256) void k_gates(
    const float* __restrict__ gi_mat, const int* __restrict__ gi_rows,
    const float* __restrict__ gh, const float* __restrict__ h_in,
    float* __restrict__ h_out) {
  int idx = blockIdx.x * 256 + threadIdx.x;
  int b = idx >> 9, j = idx & 511;
  int gr = gi_rows ? gi_rows[b] : b;
  const float* gi = gi_mat + (size_t)gr * 1536;
  const float* gp = gh + (size_t)b * 1536;
  float ir = gi[j], iz = gi[512 + j], in_ = gi[1024 + j];
  float hr = gp[j], hz = gp[512 + j], hn = gp[1024 + j];
  float r = xla_sigmoid(__fadd_rn(ir, hr));
  float u = xla_sigmoid(__fadd_rn(iz, hz));
  float n = xla_tanh(__fadd_rn(in_, __fmul_rn(r, hn)));
  float h = h_in[(size_t)b * 512 + j];
  float t1 = __fmul_rn(__fsub_rn(1.0f, u), n);
  float t2 = __fmul_rn(u, h);
  h_out[(size_t)b * 512 + j] = __fadd_rn(t1, t2);
}

__global__ __launch_bounds__(256) void k_sample(
    const float* __restrict__ logits, int* __restrict__ cur,
    int* __restrict__ finished, int* __restrict__ outTok,
    int t, uint32_t sk0, uint32_t sk1) {
  const int row = blockIdx.x;
  const int tid = threadIdx.x;
  __shared__ float sl[kVoc];
  __shared__ uint32_t skeys[kVoc];
  __shared__ int   redi[4];
  __shared__ float redf[4];
  __shared__ int   redix[4];

  const float* lp = logits + (size_t)row * kVoc;
  for (int c = tid; c < kVoc; c += 256) {
    float v = lp[c];
    if (c == kBos || c == kPad) v = kNeg;
    if (c == kEos && t < 1 + kEffMin) v = kNeg;
    sl[c] = v;
    uint32_t u = __float_as_uint(v);
    skeys[c] = u ^ ((u >> 31) ? 0xFFFFFFFFu : 0x80000000u);
  }
  __syncthreads();

  uint32_t prefix = 0u;
  for (int b = 31; b >= 0; --b) {
    uint32_t trial = prefix | (1u << b);
    int cnt = 0;
    for (int c = tid; c < kVoc; c += 256) cnt += (skeys[c] >= trial) ? 1 : 0;
#pragma unroll
    for (int off = 32; off; off >>= 1) cnt += __shfl_down(cnt, off, 64);
    __syncthreads();
    if ((tid & 63) == 0) redi[tid >> 6] = cnt;
    __syncthreads();
    int total = redi[0] + redi[1] + redi[2] + redi[3];
    if (total >= kTopK) prefix = trial;
  }

  float best = -3.4e38f; int bidx = kVoc;
  for (int c = tid; c < kVoc; c += 256) {
    if (skeys[c] >= prefix) {
      uint32_t idx = (uint32_t)row * (uint32_t)kVoc + (uint32_t)c;
      uint32_t w1, w2, bits;
#if PARTITIONABLE
      tf2x32(sk0, sk1, 0u, idx, w1, w2);
      bits = w1 ^ w2;
#else
      const uint32_t HH = (uint32_t)((uint64_t)kBatch * kVoc / 2);
      if (idx < HH) { tf2x32(sk0, sk1, idx, idx + HH, w1, w2); bits = w1; }
      else          { tf2x32(sk0, sk1, idx - HH, idx, w1, w2); bits = w2; }
#endif
      uint32_t fb = (bits >> 9) | 0x3f800000u;
      float uf = __fsub_rn(__uint_as_float(fb), 1.0f);
      if (uf == 0.0f) uf = kTiny;
      float g = -logf(-logf(uf));
      float tot = __fadd_rn(g, sl[c]);
      if (tot > best || (tot == best && c < bidx)) { best = tot; bidx = c; }
    }
  }
#pragma unroll
  for (int off = 32; off; off >>= 1) {
    float ov = __shfl_down(best, off, 64);
    int   oi = __shfl_down(bidx, off, 64);
    if (ov > best || (ov == best && oi < bidx)) { best = ov; bidx = oi; }
  }
  if ((tid & 63) == 0) { redf[tid >> 6] = best; redix[tid >> 6] = bidx; }
  __syncthreads();
  if (tid == 0) {
    for (int w = 1; w < 4; ++w) {
      if (redf[w] > best || (redf[w] == best && redix[w] < bidx)) {
        best = redf[w]; bidx = redix[w];
      }
    }
    int fin = finished[row];
    int nxt = fin ? kPad : bidx;
    outTok[(size_t)row * kMaxLen + t] = nxt;
    cur[row] = nxt;
    finished[row] = fin | (nxt == kEos);
  }
}

__global__ __launch_bounds__(256) void k_init(int* cur, int* finished, int* outTok) {
  int i = blockIdx.x * 256 + threadIdx.x;
  if (i < kBatch) {
    cur[i] = kBos;
    finished[i] = 0;
    outTok[(size_t)i * kMaxLen] = kBos;
  }
}

extern "C" void kernel_launch(void* const* d_in, const int* in_sizes, int n_in,
                              void* d_out, int out_size, void* d_ws, size_t ws_size,
                              hipStream_t stream) {
  (void)in_sizes; (void)n_in; (void)out_size; (void)ws_size;
  const float* z      = (const float*)d_in[0];
  const float* embed  = (const float*)d_in[1];
  const float* w_lh   = (const float*)d_in[2];
  const float* b_lh   = (const float*)d_in[3];
  const float* w_ih0  = (const float*)d_in[4];
  const float* w_hh0  = (const float*)d_in[5];
  const float* b_ih0  = (const float*)d_in[6];
  const float* b_hh0  = (const float*)d_in[7];
  const float* w_ih1  = (const float*)d_in[8];
  const float* w_hh1  = (const float*)d_in[9];
  const float* b_ih1  = (const float*)d_in[10];
  const float* b_hh1  = (const float*)d_in[11];
  const float* w_out  = (const float*)d_in[12];
  const float* b_out  = (const float*)d_in[13];
  int* out = (int*)d_out;

  float* p = (float*)d_ws;
  float* wt_hh0 = p; p += (size_t)512 * 1536;
  float* wt_ih1 = p; p += (size_t)512 * 1536;
  float* wt_hh1 = p; p += (size_t)512 * 1536;
  float* wt_out = p; p += (size_t)512 * 2048;
  float* wt_ih0 = p; p += (size_t)128 * 1536;
  float* wt_lh  = p; p += (size_t)128 * 1024;
  float* Eih0   = p; p += (size_t)kVoc * 1536;
  float* h0A = p; p += (size_t)kBatch * kHid;
  float* h0B = p; p += (size_t)kBatch * kHid;
  float* h1A = p; p += (size_t)kBatch * kHid;
  float* h1B = p; p += (size_t)kBatch * kHid;
  float* ghA = p; p += (size_t)kBatch * 1536;
  float* gi1 = p; p += (size_t)kBatch * 1536;
  float* logits = ghA;                    // spans ghA+gi1 (both dead when written)
  int* curTok   = (int*)p;
  int* finished = curTok + kBatch;

  dim3 blk(256);
  dim3 tblk(32, 8);

  // one-time (re-run every call; cheap, deterministic)
  k_transpose<<<dim3(16, 48), tblk, 0, stream>>>(w_hh0, wt_hh0, 1536, 512);
  k_transpose<<<dim3(16, 48), tblk, 0, stream>>>(w_ih1, wt_ih1, 1536, 512);
  k_transpose<<<dim3(16, 48), tblk, 0, stream>>>(w_hh1, wt_hh1, 1536, 512);
  k_transpose<<<dim3(16, 64), tblk, 0, stream>>>(w_out, wt_out, 2048, 512);
  k_transpose<<<dim3(4, 48),  tblk, 0, stream>>>(w_ih0, wt_ih0, 1536, 128);
  k_transpose<<<dim3(4, 32),  tblk, 0, stream>>>(w_lh,  wt_lh,  1024, 128);

  // Eih0 = embed @ w_ih0^T + b_ih0  [2048,1536]
  gemm2<0><<<dim3(12, 16, 1), blk, 0, stream>>>(
      embed, wt_ih0, b_ih0, Eih0, embed, wt_ih0, b_ih0, Eih0,
      kEmb, 1536, 1536, kEmb);
  // h0 = tanh(z @ w_lh[0:512]^T + b); h1 likewise (dual launch)
  gemm2<1><<<dim3(4, 32, 2), blk, 0, stream>>>(
      z, wt_lh,        b_lh,        h0A,
      z, wt_lh + 512,  b_lh + 512,  h1A,
      kEmb, 1024, kHid, kEmb);
  k_init<<<dim3((kBatch + 255) / 256), blk, 0, stream>>>(curTok, finished, out);

  uint32_t key0 = 0u, key1 = 1u;
  for (int t = 1; t < kMaxLen; ++t) {
    uint32_t nk0, nk1, s0, s1;
#if PARTITIONABLE
    tf2x32(key0, key1, 0u, 0u, nk0, nk1);
    tf2x32(key0, key1, 0u, 1u, s0, s1);
#else
    uint32_t a0, b0w, a1, b1w;
    tf2x32(key0, key1, 0u, 2u, a0, b0w);
    tf2x32(key0, key1, 1u, 3u, a1, b1w);
    nk0 = a0; nk1 = a1; s0 = b0w; s1 = b1w;
#endif
    const float* h0in = (t & 1) ? h0A : h0B;  float* h0out = (t & 1) ? h0B : h0A;
    const float* h1in = (t & 1) ? h1A : h1B;  float* h1out = (t & 1) ? h1B : h1A;

    // gh0 = h0in @ w_hh0^T + b_hh0
    gemm2<0><<<dim3(12, 32, 1), blk, 0, stream>>>(
        h0in, wt_hh0, b_hh0, ghA, h0in, wt_hh0, b_hh0, ghA,
        kHid, 1536, 1536, kHid);
    k_gates<<<dim3(kBatch * kHid / 256), blk, 0, stream>>>(
        Eih0, curTok, ghA, h0in, h0out);
    // gi1 = h0out @ w_ih1^T ; gh1 = h1in @ w_hh1^T  (independent -> dual)
    gemm2<0><<<dim3(12, 32, 2), blk, 0, stream>>>(
        h0out, wt_ih1, b_ih1, gi1,
        h1in,  wt_hh1, b_hh1, ghA,
        kHid, 1536, 1536, kHid);
    k_gates<<<dim3(kBatch * kHid / 256), blk, 0, stream>>>(
        gi1, nullptr, ghA, h1in, h1out);
    // logits = h1out @ w_out^T + b_out
    gemm2<0><<<dim3(16, 32, 1), blk, 0, stream>>>(
        h1out, wt_out, b_out, logits, h1out, wt_out, b_out, logits,
        kHid, 2048, 2048, kHid);
    k_sample<<<dim3(kBatch), blk, 0, stream>>>(logits, curTok, finished, out, t, s0, s1);

    key0 = nk0; key1 = nk1;
  }
}

// Round 6
// 20113.924 us; speedup vs baseline: 1.4680x; 1.4000x over previous
//
#include <hip/hip_runtime.h>
#include <cstdint>
#include <cstddef>

#ifndef PARTITIONABLE
#define PARTITIONABLE 1
#endif

namespace {
constexpr int kBatch  = 4096;
constexpr int kEmb    = 128;
constexpr int kHid    = 512;
constexpr int kVoc    = 2048;
constexpr int kMaxLen = 64;
constexpr int kTopK   = 40;
constexpr int kBos = 1, kEos = 2, kPad = 0;
constexpr int kEffMin = 20;
constexpr float kNeg  = -1.0e9f;
constexpr float kTiny = 1.17549435082228751e-38f;
}

typedef __bf16 bf16x8 __attribute__((ext_vector_type(8)));
typedef float  f32x4  __attribute__((ext_vector_type(4)));

__host__ __device__ inline void tf2x32(uint32_t k0, uint32_t k1,
                                       uint32_t x0, uint32_t x1,
                                       uint32_t& o0, uint32_t& o1) {
  uint32_t ks0 = k0, ks1 = k1, ks2 = k0 ^ k1 ^ 0x1BD11BDAu;
  x0 += ks0; x1 += ks1;
#define TFR(r) { x0 += x1; x1 = (x1 << (r)) | (x1 >> (32 - (r))); x1 ^= x0; }
  TFR(13) TFR(15) TFR(26) TFR(6)   x0 += ks1; x1 += ks2 + 1u;
  TFR(17) TFR(29) TFR(16) TFR(24)  x0 += ks2; x1 += ks0 + 2u;
  TFR(13) TFR(15) TFR(26) TFR(6)   x0 += ks0; x1 += ks1 + 3u;
  TFR(17) TFR(29) TFR(16) TFR(24)  x0 += ks1; x1 += ks2 + 4u;
  TFR(13) TFR(15) TFR(26) TFR(6)   x0 += ks2; x1 += ks0 + 5u;
#undef TFR
  o0 = x0; o1 = x1;
}

__device__ __forceinline__ float xla_tanh(float x) {
  float ax = fabsf(x);
  float xc = fminf(fmaxf(x, -9.0f), 9.0f);
  float x2 = __fmul_rn(xc, xc);
  float num = -2.76076847742355e-16f;
  num = __fadd_rn(__fmul_rn(x2, num), 2.00018790482477e-13f);
  num = __fadd_rn(__fmul_rn(x2, num), -8.60467152213735e-11f);
  num = __fadd_rn(__fmul_rn(x2, num), 5.12229709037114e-08f);
  num = __fadd_rn(__fmul_rn(x2, num), 1.48572235717979e-05f);
  num = __fadd_rn(__fmul_rn(x2, num), 6.37261928875436e-04f);
  num = __fadd_rn(__fmul_rn(x2, num), 4.89352455891786e-03f);
  num = __fmul_rn(xc, num);
  float den = 1.19825839466702e-06f;
  den = __fadd_rn(__fmul_rn(x2, den), 1.18534705686654e-04f);
  den = __fadd_rn(__fmul_rn(x2, den), 2.26843463243900e-03f);
  den = __fadd_rn(__fmul_rn(x2, den), 4.89352518554385e-03f);
  return (ax < 4.0e-04f) ? x : __fdiv_rn(num, den);
}

__device__ __forceinline__ float xla_sigmoid(float x) {
  return __fdiv_rn(1.0f, __fadd_rn(1.0f, expf(-x)));
}

__device__ __forceinline__ void gl_lds16(const void* g, void* l) {
  __builtin_amdgcn_global_load_lds(
      (const __attribute__((address_space(1))) void*)g,
      (__attribute__((address_space(3))) void*)l, 16, 0, 0);
}

// ---------------- f32 vector GEMM (init only; proven rounds 1-2) ------------
template <int ACT>
__global__ __launch_bounds__(256) void gemm2(
    const float* __restrict__ A0, const float* __restrict__ B0,
    const float* __restrict__ bias0, float* __restrict__ C0,
    const float* __restrict__ A1, const float* __restrict__ B1,
    const float* __restrict__ bias1, float* __restrict__ C1,
    int lda, int ldb, int ldc, int K) {
  __shared__ __attribute__((aligned(16))) float As[2][128 * 16];
  __shared__ __attribute__((aligned(16))) float Bs[2][16 * 128];

  const float* A    = blockIdx.z ? A1 : A0;
  const float* Bt   = blockIdx.z ? B1 : B0;
  const float* bias = blockIdx.z ? bias1 : bias0;
  float*       C    = blockIdx.z ? C1 : C0;

  const int tid = threadIdx.x;
  const int w = tid >> 6, l = tid & 63;
  const int bm = blockIdx.y * 128;
  const int bn = blockIdx.x * 128;
  const int tx = tid & 15, ty = tid >> 4;
  const int t3 = ty & 3;

  const int arow  = w * 16 + (l >> 2);
  const int agran = (l & 3) ^ ((l >> 2) & 3);
  const float* pA = A + (size_t)(bm + arow) * lda + agran * 4;
  const int bk = w * 2 + (l >> 5);
  const int bnc = (l & 31) * 4;
  const float* pB = Bt + (size_t)bk * ldb + bn + bnc;

  float acc[8][8];
#pragma unroll
  for (int i = 0; i < 8; ++i)
#pragma unroll
    for (int j = 0; j < 8; ++j) acc[i][j] = 0.0f;

  const int nt = K >> 4;
  gl_lds16(pA,            &As[0][w * 256]);
  gl_lds16(pA + 64 * lda, &As[0][(4 + w) * 256]);
  gl_lds16(pB,            &Bs[0][w * 256]);
  gl_lds16(pB + (size_t)8 * ldb, &Bs[0][(4 + w) * 256]);
  __syncthreads();

  for (int t = 0; t < nt; ++t) {
    const int cur = t & 1;
    if (t + 1 < nt) {
      const float* qA = pA + (t + 1) * 16;
      const float* qB = pB + (size_t)(t + 1) * 16 * ldb;
      gl_lds16(qA,            &As[cur ^ 1][w * 256]);
      gl_lds16(qA + 64 * lda, &As[cur ^ 1][(4 + w) * 256]);
      gl_lds16(qB,            &Bs[cur ^ 1][w * 256]);
      gl_lds16(qB + (size_t)8 * ldb, &Bs[cur ^ 1][(4 + w) * 256]);
    }
    const float* as = As[cur];
    const float* bs = Bs[cur];
#pragma unroll
    for (int g = 0; g < 4; ++g) {
      float4 bv0[4], bv1[4];
#pragma unroll
      for (int q = 0; q < 4; ++q) {
        bv0[q] = *(const float4*)&bs[(g * 4 + q) * 128 + tx * 4];
        bv1[q] = *(const float4*)&bs[(g * 4 + q) * 128 + 64 + tx * 4];
      }
#pragma unroll
      for (int ii = 0; ii < 8; ++ii) {
        float4 a = *(const float4*)&as[(ty + 16 * ii) * 16 + ((g ^ t3) * 4)];
        float ak[4] = {a.x, a.y, a.z, a.w};
#pragma unroll
        for (int q = 0; q < 4; ++q) {
          const float av_ = ak[q];
          const float4 b0 = bv0[q], b1 = bv1[q];
          acc[ii][0] += av_ * b0.x; acc[ii][1] += av_ * b0.y;
          acc[ii][2] += av_ * b0.z; acc[ii][3] += av_ * b0.w;
          acc[ii][4] += av_ * b1.x; acc[ii][5] += av_ * b1.y;
          acc[ii][6] += av_ * b1.z; acc[ii][7] += av_ * b1.w;
        }
      }
    }
    __syncthreads();
  }

  const int c0 = bn + tx * 4, c1 = bn + 64 + tx * 4;
  const float4 bs0 = *(const float4*)&bias[c0];
  const float4 bs1 = *(const float4*)&bias[c1];
#pragma unroll
  for (int ii = 0; ii < 8; ++ii) {
    const int r = bm + ty + 16 * ii;
    float4 o0, o1;
    o0.x = acc[ii][0] + bs0.x; o0.y = acc[ii][1] + bs0.y;
    o0.z = acc[ii][2] + bs0.z; o0.w = acc[ii][3] + bs0.w;
    o1.x = acc[ii][4] + bs1.x; o1.y = acc[ii][5] + bs1.y;
    o1.z = acc[ii][6] + bs1.z; o1.w = acc[ii][7] + bs1.w;
    if (ACT == 1) {
      o0.x = xla_tanh(o0.x); o0.y = xla_tanh(o0.y);
      o0.z = xla_tanh(o0.z); o0.w = xla_tanh(o0.w);
      o1.x = xla_tanh(o1.x); o1.y = xla_tanh(o1.y);
      o1.z = xla_tanh(o1.z); o1.w = xla_tanh(o1.w);
    }
    *(float4*)(C + (size_t)r * ldc + c0) = o0;
    *(float4*)(C + (size_t)r * ldc + c1) = o1;
  }
}

// ---------------- bf16x3 split-precision MFMA GEMM (9-term = exact mults) ---
// value = p0+p1+p2 (EXACT split of f32). Full expansion: 9 products, each
// EXACT in f32 (8x8-bit mantissas); only error = f32 accumulation rounding,
// same class as a plain f32 GEMM. Accumulated small->large.
struct GemmArgs {
  const __bf16 *a0, *a1, *a2;
  const __bf16 *b0, *b1, *b2;
  const float* bias;
  float* c;
};

__global__ __launch_bounds__(256, 3) void gemm_mx3(
    GemmArgs g0, GemmArgs g1, int N) {
  __shared__ __attribute__((aligned(16))) __bf16 lds[6 * 4096];  // 48 KiB

  const GemmArgs g = blockIdx.z ? g1 : g0;
  const int tid = threadIdx.x;
  const int bm = blockIdx.y * 128;
  const int bn = blockIdx.x * 128;
  const int lane = tid & 63;
  const int w  = tid >> 6;
  const int wm = w & 1;
  const int wn = w >> 1;
  const int l15 = lane & 15;
  const int kge = (lane >> 4) * 8;

  const int srow = tid >> 2;
  const int sge  = (tid & 3) * 8;
  const __bf16* tp[6];
  tp[0] = g.a0 + (size_t)(bm + srow) * 512 + sge;
  tp[1] = g.a1 + (size_t)(bm + srow) * 512 + sge;
  tp[2] = g.a2 + (size_t)(bm + srow) * 512 + sge;
  tp[3] = g.b0 + (size_t)(bn + srow) * 512 + sge;
  tp[4] = g.b1 + (size_t)(bn + srow) * 512 + sge;
  tp[5] = g.b2 + (size_t)(bn + srow) * 512 + sge;

  int aoff[4], boff[4];
#pragma unroll
  for (int i = 0; i < 4; ++i) {
    aoff[i] = (wm * 64 + i * 16 + l15) * 32 + kge;
    boff[i] = (wn * 64 + i * 16 + l15) * 32 + kge;
  }

  f32x4 acc[4][4] = {};

  for (int s = 0; s < 16; ++s) {
    const int k0 = s * 32;
#pragma unroll
    for (int p = 0; p < 6; ++p) {
      gl_lds16(tp[p] + k0,                    &lds[p * 4096 + w * 512]);
      gl_lds16(tp[p] + (size_t)64 * 512 + k0, &lds[p * 4096 + 2048 + w * 512]);
    }
    __syncthreads();

    bf16x8 Af[3][4];
#pragma unroll
    for (int mi = 0; mi < 4; ++mi) {
      Af[0][mi] = *(const bf16x8*)&lds[0 * 4096 + aoff[mi]];
      Af[1][mi] = *(const bf16x8*)&lds[1 * 4096 + aoff[mi]];
      Af[2][mi] = *(const bf16x8*)&lds[2 * 4096 + aoff[mi]];
    }
#pragma unroll
    for (int nj = 0; nj < 4; ++nj) {
      bf16x8 B0 = *(const bf16x8*)&lds[3 * 4096 + boff[nj]];
      bf16x8 B1 = *(const bf16x8*)&lds[4 * 4096 + boff[nj]];
      bf16x8 B2 = *(const bf16x8*)&lds[5 * 4096 + boff[nj]];
#pragma unroll
      for (int mi = 0; mi < 4; ++mi) {
        f32x4 c = acc[mi][nj];
        // 9 exact products, small -> large
        c = __builtin_amdgcn_mfma_f32_16x16x32_bf16(Af[2][mi], B2, c, 0, 0, 0);
        c = __builtin_amdgcn_mfma_f32_16x16x32_bf16(Af[2][mi], B1, c, 0, 0, 0);
        c = __builtin_amdgcn_mfma_f32_16x16x32_bf16(Af[1][mi], B2, c, 0, 0, 0);
        c = __builtin_amdgcn_mfma_f32_16x16x32_bf16(Af[2][mi], B0, c, 0, 0, 0);
        c = __builtin_amdgcn_mfma_f32_16x16x32_bf16(Af[1][mi], B1, c, 0, 0, 0);
        c = __builtin_amdgcn_mfma_f32_16x16x32_bf16(Af[0][mi], B2, c, 0, 0, 0);
        c = __builtin_amdgcn_mfma_f32_16x16x32_bf16(Af[1][mi], B0, c, 0, 0, 0);
        c = __builtin_amdgcn_mfma_f32_16x16x32_bf16(Af[0][mi], B1, c, 0, 0, 0);
        c = __builtin_amdgcn_mfma_f32_16x16x32_bf16(Af[0][mi], B0, c, 0, 0, 0);
        acc[mi][nj] = c;
      }
    }
    __syncthreads();
  }

#pragma unroll
  for (int mi = 0; mi < 4; ++mi) {
    const int row0 = bm + wm * 64 + mi * 16 + (lane >> 4) * 4;
#pragma unroll
    for (int nj = 0; nj < 4; ++nj) {
      const int col = bn + wn * 64 + nj * 16 + l15;
      const float bv = g.bias[col];
      f32x4 v = acc[mi][nj];
#pragma unroll
      for (int r = 0; r < 4; ++r)
        g.c[(size_t)(row0 + r) * N + col] = v[r] + bv;
    }
  }
}

// ---------------- splitters --------------------------------------------------
__device__ __forceinline__ void split3(float a, __bf16& a0, __bf16& a1, __bf16& a2) {
  a0 = (__bf16)a;
  float r1 = __fsub_rn(a, (float)a0);
  a1 = (__bf16)r1;
  float r2 = __fsub_rn(r1, (float)a1);
  a2 = (__bf16)r2;   // exact: 3x8 mantissa bits cover f32's 24
}

__global__ __launch_bounds__(256) void k_split(
    const float* __restrict__ in, __bf16* __restrict__ p0,
    __bf16* __restrict__ p1, __bf16* __restrict__ p2, int total) {
  int i = blockIdx.x * 256 + threadIdx.x;
  if (i >= total) return;
  __bf16 a0, a1, a2;
  split3(in[i], a0, a1, a2);
  p0[i] = a0; p1[i] = a1; p2[i] = a2;
}

__global__ __launch_bounds__(256) void k_transpose(
    const float* __restrict__ in, float* __restrict__ out, int R, int C) {
  __shared__ float tile[32][33];
  int c0 = blockIdx.x * 32, r0 = blockIdx.y * 32;
  int x = threadIdx.x, y0 = threadIdx.y;
  for (int i = y0; i < 32; i += 8) {
    int r = r0 + i, c = c0 + x;
    tile[i][x] = (r < R && c < C) ? in[(size_t)r * C + c] : 0.0f;
  }
  __syncthreads();
  for (int i = y0; i < 32; i += 8) {
    int orow = c0 + i, oc = r0 + x;
    if (orow < C && oc < R) out[(size_t)orow * R + oc] = tile[x][i];
  }
}

// GRU gates; h state lives ONLY as exact bf16x3 planes (p0+p1+p2 == h bitwise).
__global__ __launch_bounds__(256) void k_gates(
    const float* __restrict__ gi_mat, const int* __restrict__ gi_rows,
    const float* __restrict__ gh,
    __bf16* __restrict__ p0, __bf16* __restrict__ p1, __bf16* __restrict__ p2) {
  int idx = blockIdx.x * 256 + threadIdx.x;
  int b = idx >> 9, j = idx & 511;
  int gr = gi_rows ? gi_rows[b] : b;
  const float* gi = gi_mat + (size_t)gr * 1536;
  const float* gp = gh + (size_t)b * 1536;
  float ir = gi[j], iz = gi[512 + j], in_ = gi[1024 + j];
  float hr = gp[j], hz = gp[512 + j], hn = gp[1024 + j];
  float r = xla_sigmoid(__fadd_rn(ir, hr));
  float u = xla_sigmoid(__fadd_rn(iz, hz));
  float n = xla_tanh(__fadd_rn(in_, __fmul_rn(r, hn)));
  float hold = __fadd_rn(__fadd_rn((float)p0[idx], (float)p1[idx]), (float)p2[idx]);
  float t1 = __fmul_rn(__fsub_rn(1.0f, u), n);
  float t2 = __fmul_rn(u, hold);
  float hnew = __fadd_rn(t1, t2);
  __bf16 a0, a1, a2;
  split3(hnew, a0, a1, a2);
  p0[idx] = a0; p1[idx] = a1; p2[idx] = a2;
}

// ---------------- sampling ---------------------------------------------------
__global__ __launch_bounds__(256) void k_sample(
    const float* __restrict__ logits, int* __restrict__ cur,
    int* __restrict__ finished, int* __restrict__ outTok,
    int t, uint32_t sk0, uint32_t sk1) {
  const int row = blockIdx.x;
  const int tid = threadIdx.x;
  __shared__ float sl[kVoc];
  __shared__ uint32_t skeys[kVoc];
  __shared__ int   redi[4];
  __shared__ float redf[4];
  __shared__ int   redix[4];

  const float* lp = logits + (size_t)row * kVoc;
  for (int c = tid; c < kVoc; c += 256) {
    float v = lp[c];
    if (c == kBos || c == kPad) v = kNeg;
    if (c == kEos && t < 1 + kEffMin) v = kNeg;
    sl[c] = v;
    uint32_t u = __float_as_uint(v);
    skeys[c] = u ^ ((u >> 31) ? 0xFFFFFFFFu : 0x80000000u);
  }
  __syncthreads();

  uint32_t prefix = 0u;
  for (int b = 31; b >= 0; --b) {
    uint32_t trial = prefix | (1u << b);
    int cnt = 0;
    for (int c = tid; c < kVoc; c += 256) cnt += (skeys[c] >= trial) ? 1 : 0;
#pragma unroll
    for (int off = 32; off; off >>= 1) cnt += __shfl_down(cnt, off, 64);
    __syncthreads();
    if ((tid & 63) == 0) redi[tid >> 6] = cnt;
    __syncthreads();
    int total = redi[0] + redi[1] + redi[2] + redi[3];
    if (total >= kTopK) prefix = trial;
  }

  float best = -3.4e38f; int bidx = kVoc;
  for (int c = tid; c < kVoc; c += 256) {
    if (skeys[c] >= prefix) {
      uint32_t idx = (uint32_t)row * (uint32_t)kVoc + (uint32_t)c;
      uint32_t w1, w2, bits;
#if PARTITIONABLE
      tf2x32(sk0, sk1, 0u, idx, w1, w2);
      bits = w1 ^ w2;
#else
      const uint32_t HH = (uint32_t)((uint64_t)kBatch * kVoc / 2);
      if (idx < HH) { tf2x32(sk0, sk1, idx, idx + HH, w1, w2); bits = w1; }
      else          { tf2x32(sk0, sk1, idx - HH, idx, w1, w2); bits = w2; }
#endif
      uint32_t fb = (bits >> 9) | 0x3f800000u;
      float uf = __fsub_rn(__uint_as_float(fb), 1.0f);
      if (uf == 0.0f) uf = kTiny;
      float g = -logf(-logf(uf));
      float tot = __fadd_rn(g, sl[c]);
      if (tot > best || (tot == best && c < bidx)) { best = tot; bidx = c; }
    }
  }
#pragma unroll
  for (int off = 32; off; off >>= 1) {
    float ov = __shfl_down(best, off, 64);
    int   oi = __shfl_down(bidx, off, 64);
    if (ov > best || (ov == best && oi < bidx)) { best = ov; bidx = oi; }
  }
  if ((tid & 63) == 0) { redf[tid >> 6] = best; redix[tid >> 6] = bidx; }
  __syncthreads();
  if (tid == 0) {
    for (int w = 1; w < 4; ++w) {
      if (redf[w] > best || (redf[w] == best && redix[w] < bidx)) {
        best = redf[w]; bidx = redix[w];
      }
    }
    int fin = finished[row];
    int nxt = fin ? kPad : bidx;
    outTok[(size_t)row * kMaxLen + t] = nxt;
    cur[row] = nxt;
    finished[row] = fin | (nxt == kEos);
  }
}

__global__ __launch_bounds__(256) void k_init(int* cur, int* finished, int* outTok) {
  int i = blockIdx.x * 256 + threadIdx.x;
  if (i < kBatch) {
    cur[i] = kBos;
    finished[i] = 0;
    outTok[(size_t)i * kMaxLen] = kBos;
  }
}

extern "C" void kernel_launch(void* const* d_in, const int* in_sizes, int n_in,
                              void* d_out, int out_size, void* d_ws, size_t ws_size,
                              hipStream_t stream) {
  (void)in_sizes; (void)n_in; (void)out_size; (void)ws_size;
  const float* z      = (const float*)d_in[0];
  const float* embed  = (const float*)d_in[1];
  const float* w_lh   = (const float*)d_in[2];
  const float* b_lh   = (const float*)d_in[3];
  const float* w_ih0  = (const float*)d_in[4];
  const float* w_hh0  = (const float*)d_in[5];
  const float* b_ih0  = (const float*)d_in[6];
  const float* b_hh0  = (const float*)d_in[7];
  const float* w_ih1  = (const float*)d_in[8];
  const float* w_hh1  = (const float*)d_in[9];
  const float* b_ih1  = (const float*)d_in[10];
  const float* b_hh1  = (const float*)d_in[11];
  const float* w_out  = (const float*)d_in[12];
  const float* b_out  = (const float*)d_in[13];
  int* out = (int*)d_out;

  // ---- workspace layout: identical to round 5 (108.6 MB, state first) ----
  char* base = (char*)d_ws;
  int* curTok   = (int*)base;
  int* finished = curTok + kBatch;
  __bf16* q = (__bf16*)(base + 32768);
  __bf16* whh0[3]; __bf16* wih1[3]; __bf16* whh1[3]; __bf16* wout[3];
  for (int i = 0; i < 3; ++i) { whh0[i] = q; q += (size_t)1536 * 512; }
  for (int i = 0; i < 3; ++i) { wih1[i] = q; q += (size_t)1536 * 512; }
  for (int i = 0; i < 3; ++i) { whh1[i] = q; q += (size_t)1536 * 512; }
  for (int i = 0; i < 3; ++i) { wout[i] = q; q += (size_t)2048 * 512; }
  __bf16* hs0[3]; __bf16* hs1[3];
  for (int i = 0; i < 3; ++i) { hs0[i] = q; q += (size_t)kBatch * kHid; }
  for (int i = 0; i < 3; ++i) { hs1[i] = q; q += (size_t)kBatch * kHid; }
  float* f = (float*)q;
  float* Eih0 = f; f += (size_t)kVoc * 1536;
  float* ghA  = f; f += (size_t)kBatch * 1536;
  float* gi1  = f; f += (size_t)kBatch * 1536;
  float* logits = ghA;                       // spans ghA+gi1 (both dead then)
  float* wt_ih0 = ghA;                       // init-only aliases
  float* wt_lh  = ghA + (size_t)128 * 1536;
  float* h0tmp  = gi1;
  float* h1tmp  = gi1 + (size_t)kBatch * kHid;

  dim3 blk(256);
  dim3 tblk(32, 8);

  // ---- one-time setup ----
  k_transpose<<<dim3(4, 48), tblk, 0, stream>>>(w_ih0, wt_ih0, 1536, 128);
  k_transpose<<<dim3(4, 32), tblk, 0, stream>>>(w_lh,  wt_lh,  1024, 128);
  k_split<<<dim3(1536 * 512 / 256), blk, 0, stream>>>(w_hh0, whh0[0], whh0[1], whh0[2], 1536 * 512);
  k_split<<<dim3(1536 * 512 / 256), blk, 0, stream>>>(w_ih1, wih1[0], wih1[1], wih1[2], 1536 * 512);
  k_split<<<dim3(1536 * 512 / 256), blk, 0, stream>>>(w_hh1, whh1[0], whh1[1], whh1[2], 1536 * 512);
  k_split<<<dim3(2048 * 512 / 256), blk, 0, stream>>>(w_out, wout[0], wout[1], wout[2], 2048 * 512);

  gemm2<0><<<dim3(12, 16, 1), blk, 0, stream>>>(
      embed, wt_ih0, b_ih0, Eih0, embed, wt_ih0, b_ih0, Eih0,
      kEmb, 1536, 1536, kEmb);
  gemm2<1><<<dim3(4, 32, 2), blk, 0, stream>>>(
      z, wt_lh,       b_lh,       h0tmp,
      z, wt_lh + 512, b_lh + 512, h1tmp,
      kEmb, 1024, kHid, kEmb);
  k_split<<<dim3(kBatch * kHid / 256), blk, 0, stream>>>(h0tmp, hs0[0], hs0[1], hs0[2], kBatch * kHid);
  k_split<<<dim3(kBatch * kHid / 256), blk, 0, stream>>>(h1tmp, hs1[0], hs1[1], hs1[2], kBatch * kHid);
  k_init<<<dim3((kBatch + 255) / 256), blk, 0, stream>>>(curTok, finished, out);

  uint32_t key0 = 0u, key1 = 1u;   // jax.random.key(1)
  for (int t = 1; t < kMaxLen; ++t) {
    uint32_t nk0, nk1, s0, s1;
#if PARTITIONABLE
    tf2x32(key0, key1, 0u, 0u, nk0, nk1);
    tf2x32(key0, key1, 0u, 1u, s0, s1);
#else
    uint32_t a0, b0w, a1, b1w;
    tf2x32(key0, key1, 0u, 2u, a0, b0w);
    tf2x32(key0, key1, 1u, 3u, a1, b1w);
    nk0 = a0; nk1 = a1; s0 = b0w; s1 = b1w;
#endif

    GemmArgs ga0{hs0[0], hs0[1], hs0[2], whh0[0], whh0[1], whh0[2], b_hh0, ghA};
    gemm_mx3<<<dim3(12, 32, 1), blk, 0, stream>>>(ga0, ga0, 1536);
    k_gates<<<dim3(kBatch * kHid / 256), blk, 0, stream>>>(
        Eih0, curTok, ghA, hs0[0], hs0[1], hs0[2]);

    GemmArgs gia{hs0[0], hs0[1], hs0[2], wih1[0], wih1[1], wih1[2], b_ih1, gi1};
    GemmArgs gha{hs1[0], hs1[1], hs1[2], whh1[0], whh1[1], whh1[2], b_hh1, ghA};
    gemm_mx3<<<dim3(12, 32, 2), blk, 0, stream>>>(gia, gha, 1536);
    k_gates<<<dim3(kBatch * kHid / 256), blk, 0, stream>>>(
        gi1, nullptr, ghA, hs1[0], hs1[1], hs1[2]);

    GemmArgs gla{hs1[0], hs1[1], hs1[2], wout[0], wout[1], wout[2], b_out, logits};
    gemm_mx3<<<dim3(16, 32, 1), blk, 0, stream>>>(gla, gla, 2048);
    k_sample<<<dim3(kBatch), blk, 0, stream>>>(logits, curTok, finished, out, t, s0, s1);

    key0 = nk0; key1 = nk1;
  }
}